// Round 1
// baseline (1455.614 us; speedup 1.0000x reference)
//
#include <hip/hip_runtime.h>
#include <math.h>

#define Bv 256
#define Sv 128
#define Cv 256
#define Tv 64
#define Dv 300
#define Hv 150
#define G4v 600   // 4*H

// ------------------------------------------------------------------
// row L2 norm (length 300), one wave per row: out[r] = max(||x_r||, 1e-8)
// ------------------------------------------------------------------
__global__ __launch_bounds__(256)
void row_norm_k(const float* __restrict__ x, int rows, float* __restrict__ out)
{
    int gtid = blockIdx.x * 256 + threadIdx.x;
    int wave = gtid >> 6;
    int lane = threadIdx.x & 63;
    if (wave >= rows) return;
    const float* row = x + (size_t)wave * Dv;
    float s = 0.f;
    for (int k = lane; k < Dv; k += 64) { float v = row[k]; s += v * v; }
    #pragma unroll
    for (int off = 32; off > 0; off >>= 1) s += __shfl_down(s, off, 64);
    if (lane == 0) out[wave] = fmaxf(sqrtf(s), 1e-8f);
}

// ------------------------------------------------------------------
// G[dir][s][b][0:600] = src_emb[b][s][:] @ Wx_dir + b_dir
// tiled fp32 GEMM: M=32768 (r=b*128+s), N=600 (pad to 640), K=300
// block: 256 thr, tile 128x128x16, 8x8 per thread
// ------------------------------------------------------------------
__global__ __launch_bounds__(256)
void gemm_xw_k(const float* __restrict__ A,
               const float* __restrict__ Wf, const float* __restrict__ bf,
               const float* __restrict__ Wb, const float* __restrict__ bb,
               float* __restrict__ Gout)
{
    const int mt  = blockIdx.x;   // 0..255
    const int nt  = blockIdx.y;   // 0..4
    const int dir = blockIdx.z;   // 0..1
    const float* W    = dir ? Wb : Wf;
    const float* bias = dir ? bb : bf;
    const int r0 = mt * 128;
    const int n0 = nt * 128;
    const int tid = threadIdx.x;

    __shared__ float As[16][132];
    __shared__ float Bs[16][132];

    float acc[8][8];
    #pragma unroll
    for (int i = 0; i < 8; ++i)
        #pragma unroll
        for (int j = 0; j < 8; ++j) acc[i][j] = 0.f;

    const int ka = tid & 15, ma = tid >> 4;     // A-slab loader coords
    const int nb = tid & 127, kb = tid >> 7;    // B-slab loader coords

    for (int k0 = 0; k0 < Dv; k0 += 16) {
        #pragma unroll
        for (int p = 0; p < 8; ++p) {
            int m  = ma + p * 16;
            int kk = k0 + ka;
            As[ka][m] = (kk < Dv) ? A[(size_t)(r0 + m) * Dv + kk] : 0.f;
        }
        #pragma unroll
        for (int p = 0; p < 8; ++p) {
            int k  = kb + p * 2;
            int kk = k0 + k;
            int nn = n0 + nb;
            Bs[k][nb] = (kk < Dv && nn < G4v) ? W[(size_t)kk * G4v + nn] : 0.f;
        }
        __syncthreads();
        const int ty = tid >> 4, tx = tid & 15;
        #pragma unroll
        for (int k = 0; k < 16; ++k) {
            float a[8], bv[8];
            *(float4*)&a[0]  = *(const float4*)&As[k][ty*8];
            *(float4*)&a[4]  = *(const float4*)&As[k][ty*8+4];
            *(float4*)&bv[0] = *(const float4*)&Bs[k][tx*8];
            *(float4*)&bv[4] = *(const float4*)&Bs[k][tx*8+4];
            #pragma unroll
            for (int i = 0; i < 8; ++i)
                #pragma unroll
                for (int j = 0; j < 8; ++j)
                    acc[i][j] = fmaf(a[i], bv[j], acc[i][j]);
        }
        __syncthreads();
    }

    const int ty = tid >> 4, tx = tid & 15;
    #pragma unroll
    for (int i = 0; i < 8; ++i) {
        int r    = r0 + ty*8 + i;
        int bidx = r >> 7;      // S = 128
        int s    = r & 127;
        float* orow = Gout + ((size_t)dir * Sv * Bv + (size_t)s * Bv + bidx) * G4v;
        #pragma unroll
        for (int j4 = 0; j4 < 8; j4 += 4) {
            int n = n0 + tx*8 + j4;
            if (n < G4v) {
                float4 v;
                v.x = acc[i][j4+0] + bias[n+0];
                v.y = acc[i][j4+1] + bias[n+1];
                v.z = acc[i][j4+2] + bias[n+2];
                v.w = acc[i][j4+3] + bias[n+3];
                *(float4*)&orow[n] = v;
            }
        }
    }
}

// ------------------------------------------------------------------
// LSTM recurrence. One block per (batch, dir). 640 threads (600 active),
// thread j holds column Wh[:,j] in 150 VGPRs; h broadcast via LDS.
// ------------------------------------------------------------------
__device__ __forceinline__ float sigm(float x) { return 1.0f / (1.0f + expf(-x)); }

__global__ __launch_bounds__(640, 1)
void lstm_k(const float* __restrict__ G,      // [2][S][B][600], bias included
            const float* __restrict__ Wh_f, const float* __restrict__ Wh_b,
            float* __restrict__ out_src,      // [B][S][300]
            float* __restrict__ out_cell)     // [B][300]
{
    const int bid = blockIdx.x;     // 0..511
    const int b   = bid >> 1;
    const int dir = bid & 1;
    const float* Wh = dir ? Wh_b : Wh_f;
    const float* Gd = G + (size_t)dir * Sv * Bv * G4v;

    __shared__ float h_sh[Hv];
    __shared__ float g_sh[G4v];

    const int t = threadIdx.x;
    float wh[Hv];
    if (t < G4v) {
        #pragma unroll
        for (int k = 0; k < Hv; ++k) wh[k] = Wh[(size_t)k * G4v + t];
    }
    if (t < Hv) h_sh[t] = 0.f;
    float c = 0.f;
    __syncthreads();

    for (int s = 0; s < Sv; ++s) {
        int ss = dir ? (Sv - 1 - s) : s;
        if (t < G4v) {
            float g = Gd[((size_t)ss * Bv + b) * G4v + t];
            #pragma unroll
            for (int k = 0; k < Hv; ++k) g = fmaf(h_sh[k], wh[k], g);
            g_sh[t] = g;
        }
        __syncthreads();
        if (t < Hv) {
            float ig = sigm(g_sh[t]);
            float fg = sigm(g_sh[t + Hv]);
            float gg = tanhf(g_sh[t + 2*Hv]);
            float og = sigm(g_sh[t + 3*Hv]);
            c = fg * c + ig * gg;
            float h = og * tanhf(c);
            h_sh[t] = h;
            out_src[((size_t)b * Sv + ss) * (2*Hv) + dir*Hv + t] = h;
        }
        __syncthreads();
    }
    if (t < Hv) out_cell[(size_t)b * (2*Hv) + dir*Hv + t] = c;
}

// ------------------------------------------------------------------
// out[b][r][n] = emb + bias[n] + sum_q hot[b][r][q] * W[q][n]
// 64 rows per block
// ------------------------------------------------------------------
__global__ __launch_bounds__(256)
void init_enc_k(const float* __restrict__ emb, const float* __restrict__ hot,
                const float* __restrict__ W, const float* __restrict__ bias,
                int hd, float* __restrict__ outp)
{
    __shared__ float Wsh[9*300];
    __shared__ float bsh[300];
    __shared__ float hotsh[64*9];
    const int tid = threadIdx.x;
    const size_t r0 = (size_t)blockIdx.x * 64;
    for (int idx = tid; idx < hd*300; idx += 256) Wsh[idx] = W[idx];
    for (int idx = tid; idx < 300;    idx += 256) bsh[idx] = bias[idx];
    for (int idx = tid; idx < 64*hd;  idx += 256) hotsh[idx] = hot[r0*hd + idx];
    __syncthreads();
    for (int idx = tid; idx < 64*300; idx += 256) {
        int r = idx / 300;
        int n = idx - r*300;
        float v = emb[r0*300 + idx] + bsh[n];
        for (int q = 0; q < hd; ++q) v = fmaf(hotsh[r*hd+q], Wsh[q*300+n], v);
        outp[r0*300 + idx] = v;
    }
}

// ------------------------------------------------------------------
// sim[b][c][s] = dot(cmp[b,c,:], src[b,s,:]) / (cn[b,c]*sn[b,s])
// per-batch GEMM: M x 128, K=300.  block tile 64x128x16, 4x8/thread
// ------------------------------------------------------------------
__global__ __launch_bounds__(256)
void gemm_sim_k(const float* __restrict__ cmp, const float* __restrict__ src,
                const float* __restrict__ cn, const float* __restrict__ sn,
                int M, float* __restrict__ sim)
{
    const int b  = blockIdx.z;
    const int m0 = blockIdx.x * 64;
    const int tid = threadIdx.x;

    const float* A  = cmp + (size_t)b * M * Dv;    // [M,300]
    const float* Bm = src + (size_t)b * Sv * Dv;   // [128,300] (used transposed)

    __shared__ float As[16][68];
    __shared__ float Bs[16][132];

    float acc[4][8];
    #pragma unroll
    for (int i = 0; i < 4; ++i)
        #pragma unroll
        for (int j = 0; j < 8; ++j) acc[i][j] = 0.f;

    const int ka = tid & 15, mb = tid >> 4;

    for (int k0 = 0; k0 < Dv; k0 += 16) {
        int kk = k0 + ka;
        #pragma unroll
        for (int p = 0; p < 4; ++p) {
            int m = mb + p*16;
            As[ka][m] = (kk < Dv) ? A[(size_t)(m0 + m) * Dv + kk] : 0.f;
        }
        #pragma unroll
        for (int p = 0; p < 8; ++p) {
            int n = mb + p*16;   // s index
            Bs[ka][n] = (kk < Dv) ? Bm[(size_t)n * Dv + kk] : 0.f;
        }
        __syncthreads();
        const int ty = tid >> 4, tx = tid & 15;
        #pragma unroll
        for (int k = 0; k < 16; ++k) {
            float a[4], bv[8];
            *(float4*)&a[0]  = *(const float4*)&As[k][ty*4];
            *(float4*)&bv[0] = *(const float4*)&Bs[k][tx*8];
            *(float4*)&bv[4] = *(const float4*)&Bs[k][tx*8+4];
            #pragma unroll
            for (int i = 0; i < 4; ++i)
                #pragma unroll
                for (int j = 0; j < 8; ++j)
                    acc[i][j] = fmaf(a[i], bv[j], acc[i][j]);
        }
        __syncthreads();
    }

    const int ty = tid >> 4, tx = tid & 15;
    float cnv[4], snv[8];
    #pragma unroll
    for (int i = 0; i < 4; ++i) cnv[i] = cn[(size_t)b * M + m0 + ty*4 + i];
    #pragma unroll
    for (int j = 0; j < 8; ++j) snv[j] = sn[(size_t)b * Sv + tx*8 + j];
    #pragma unroll
    for (int i = 0; i < 4; ++i) {
        float* orow = sim + ((size_t)b * M + m0 + ty*4 + i) * Sv;
        #pragma unroll
        for (int j4 = 0; j4 < 8; j4 += 4) {
            float4 v;
            v.x = acc[i][j4+0] / (cnv[i] * snv[j4+0]);
            v.y = acc[i][j4+1] / (cnv[i] * snv[j4+1]);
            v.z = acc[i][j4+2] / (cnv[i] * snv[j4+2]);
            v.w = acc[i][j4+3] / (cnv[i] * snv[j4+3]);
            *(float4*)&orow[tx*8 + j4] = v;
        }
    }
}

// ------------------------------------------------------------------
// out[b][c][0:300] += sim[b][c][:] @ src_enc[b][:][0:300]
// per-batch GEMM: M x 300, K=128.  tile 64x64x16, 4x4/thread
// ------------------------------------------------------------------
__global__ __launch_bounds__(256)
void gemm_ctx_k(const float* __restrict__ sim, const float* __restrict__ enc,
                int M, float* __restrict__ outp)
{
    const int b  = blockIdx.z;
    const int m0 = blockIdx.x * 64;
    const int n0 = blockIdx.y * 64;
    const int tid = threadIdx.x;

    const float* A  = sim + (size_t)b * M * Sv;     // [M,128]
    const float* Bm = enc + (size_t)b * Sv * 300;   // [128,300]

    __shared__ float As[16][68];
    __shared__ float Bs[16][68];

    float acc[4][4];
    #pragma unroll
    for (int i = 0; i < 4; ++i)
        #pragma unroll
        for (int j = 0; j < 4; ++j) acc[i][j] = 0.f;

    const int ka  = tid & 15, mb2 = tid >> 4;
    const int nb3 = tid & 63, kb3 = tid >> 6;

    for (int k0 = 0; k0 < Sv; k0 += 16) {
        #pragma unroll
        for (int p = 0; p < 4; ++p) {
            int m = mb2 + p*16;
            As[ka][m] = A[(size_t)(m0 + m) * Sv + k0 + ka];
        }
        #pragma unroll
        for (int p = 0; p < 4; ++p) {
            int k  = kb3 + p*4;
            int nn = n0 + nb3;
            Bs[k][nb3] = (nn < 300) ? Bm[(size_t)(k0 + k) * 300 + nn] : 0.f;
        }
        __syncthreads();
        const int ty = tid >> 4, tx = tid & 15;
        #pragma unroll
        for (int k = 0; k < 16; ++k) {
            float a[4], bv[4];
            *(float4*)&a[0]  = *(const float4*)&As[k][ty*4];
            *(float4*)&bv[0] = *(const float4*)&Bs[k][tx*4];
            #pragma unroll
            for (int i = 0; i < 4; ++i)
                #pragma unroll
                for (int j = 0; j < 4; ++j)
                    acc[i][j] = fmaf(a[i], bv[j], acc[i][j]);
        }
        __syncthreads();
    }

    const int ty = tid >> 4, tx = tid & 15;
    int n = n0 + tx*4;
    if (n < 300) {
        #pragma unroll
        for (int i = 0; i < 4; ++i) {
            int row = m0 + ty*4 + i;
            float4* op = (float4*)(outp + ((size_t)b * M + row) * 300 + n);
            float4 v = *op;
            v.x += acc[i][0]; v.y += acc[i][1]; v.z += acc[i][2]; v.w += acc[i][3];
            *op = v;
        }
    }
}

// ------------------------------------------------------------------
extern "C" void kernel_launch(void* const* d_in, const int* in_sizes, int n_in,
                              void* d_out, int out_size, void* d_ws, size_t ws_size,
                              hipStream_t stream)
{
    (void)in_sizes; (void)n_in; (void)out_size; (void)ws_size;
    const float* src_emb = (const float*)d_in[0];
    const float* col_emb = (const float*)d_in[1];
    const float* tab_emb = (const float*)d_in[2];
    const float* col_hot = (const float*)d_in[3];
    const float* tab_hot = (const float*)d_in[4];
    const float* Wx_f = (const float*)d_in[5];
    const float* Wh_f = (const float*)d_in[6];
    const float* b_f  = (const float*)d_in[7];
    const float* Wx_b = (const float*)d_in[8];
    const float* Wh_b = (const float*)d_in[9];
    const float* b_b  = (const float*)d_in[10];
    const float* W_col = (const float*)d_in[11];
    const float* b_col = (const float*)d_in[12];
    const float* W_tab = (const float*)d_in[13];
    const float* b_tab = (const float*)d_in[14];

    float* out      = (float*)d_out;
    float* out_src  = out;                       // [256][128][300]
    float* out_col  = out + 9830400;             // [256][256][300]
    float* out_tab  = out + 29491200;            // [256][64][300]
    float* out_cell = out + 34406400;            // [256][300]

    float* ws = (float*)d_ws;
    float* Gbuf    = ws;                         // 2*128*256*600 = 39,321,600 floats
    float* sim_col = ws;                         // reused AFTER lstm: 8,388,608 floats
    float* sim_tab = ws + 8388608;               // 2,097,152 floats
    float* sn = ws + 39321600;                   // [B*S]  32768
    float* cn = sn + 32768;                      // [B*C]  65536
    float* tn = cn + 65536;                      // [B*T]  16384

    // 1. norms
    row_norm_k<<<32768/4, 256, 0, stream>>>(src_emb, 32768, sn);
    row_norm_k<<<65536/4, 256, 0, stream>>>(col_emb, 65536, cn);
    row_norm_k<<<16384/4, 256, 0, stream>>>(tab_emb, 16384, tn);

    // 2. input projection x@Wx + b for both directions
    gemm_xw_k<<<dim3(256, 5, 2), 256, 0, stream>>>(src_emb, Wx_f, b_f, Wx_b, b_b, Gbuf);

    // 3. recurrence
    lstm_k<<<512, 640, 0, stream>>>(Gbuf, Wh_f, Wh_b, out_src, out_cell);

    // 4. out = emb + hot@W + bias
    init_enc_k<<<65536/64, 256, 0, stream>>>(col_emb, col_hot, W_col, b_col, 9, out_col);
    init_enc_k<<<16384/64, 256, 0, stream>>>(tab_emb, tab_hot, W_tab, b_tab, 5, out_tab);

    // 5. cosine similarity (overwrites Gbuf region — must come after lstm_k)
    gemm_sim_k<<<dim3(4, 1, 256), 256, 0, stream>>>(col_emb, src_emb, cn, sn, 256, sim_col);
    gemm_sim_k<<<dim3(1, 1, 256), 256, 0, stream>>>(tab_emb, src_emb, tn, sn, 64, sim_tab);

    // 6. context accumulation
    gemm_ctx_k<<<dim3(4, 5, 256), 256, 0, stream>>>(sim_col, out_src, 256, out_col);
    gemm_ctx_k<<<dim3(1, 5, 256), 256, 0, stream>>>(sim_tab, out_src, 64, out_tab);
}